// Round 4
// baseline (2528.919 us; speedup 1.0000x reference)
//
#include <hip/hip_runtime.h>
#include <hip/hip_bf16.h>

#define T_LEN 2048
#define BATCH 64
#define DIM   256  // D
#define HID   256  // H

using f16    = _Float16;
using f16x8  = __attribute__((ext_vector_type(8))) _Float16;
using fp16x2 = __attribute__((ext_vector_type(2))) __fp16;   // cvt_pkrtz result type
using f32x4  = __attribute__((ext_vector_type(4))) float;

__device__ __forceinline__ f16x8 pack8(float4 a, float4 b)
{
    fp16x2 p0 = __builtin_amdgcn_cvt_pkrtz(a.x, a.y);
    fp16x2 p1 = __builtin_amdgcn_cvt_pkrtz(a.z, a.w);
    fp16x2 p2 = __builtin_amdgcn_cvt_pkrtz(b.x, b.y);
    fp16x2 p3 = __builtin_amdgcn_cvt_pkrtz(b.z, b.w);
    f16x8 r = { (f16)p0.x, (f16)p0.y, (f16)p1.x, (f16)p1.y,
                (f16)p2.x, (f16)p2.y, (f16)p3.x, (f16)p3.y };
    return r;
}

// ---------------------------------------------------------------------------
// Kernel 1: xp = x @ [W_ih_f; W_ih_r]^T + bias -> d_out (fp32, in-place for scan)
// BM=128, BN=128, BK=64, 4 K-iters, double-buffered LDS, register prefetch of
// the next K-tile issued before compute. 1-D grid with XCD-affine swizzle:
// all 4 N-tiles of an M-tile land on the same XCD (A panel fetched once/XCD).
// ---------------------------------------------------------------------------
__global__ __launch_bounds__(256, 2) void xproj_gemm(
    const float* __restrict__ x, const float* __restrict__ Wf,
    const float* __restrict__ Wr, const float* __restrict__ bf,
    const float* __restrict__ br, float* __restrict__ out)
{
    __shared__ __align__(16) f16 As[2][128 * 64];
    __shared__ __align__(16) f16 Bs[2][128 * 64];

    const int tid = threadIdx.x;
    const int id  = blockIdx.x;            // 0..4095
    const int xcd = id & 7;
    const int g   = id >> 3;               // 0..511
    const int bx  = xcd * 128 + (g >> 2);  // 0..1023  (M-tile)
    const int by  = g & 3;                 // 0..3     (N-tile)

    const long m0 = (long)bx * 128;
    const int  n0 = by * 128;
    const float* Bsrc = (n0 < 256) ? (Wf + (long)n0 * DIM)
                                   : (Wr + (long)(n0 - 256) * DIM);
    const int w = tid >> 6, l = tid & 63;
    const int wm = (w & 1) * 64, wn = (w >> 1) * 64;
    const int srow = tid >> 1, sseg = tid & 1;   // staging: 2 threads/row

    const float* sa_base = x + (m0 + srow) * DIM + sseg * 32;
    const float* sb_base = Bsrc + (long)srow * DIM + sseg * 32;

    float4 Ra[8], Rb[8];

    // load K-tile kk into regs
    auto LD = [&](int kk) {
        #pragma unroll
        for (int q = 0; q < 8; ++q) {
            Ra[q] = ((const float4*)(sa_base + kk))[q];
            Rb[q] = ((const float4*)(sb_base + kk))[q];
        }
    };
    // pack regs -> LDS buffer
    auto ST = [&](int buf) {
        #pragma unroll
        for (int q = 0; q < 4; ++q) {
            int c = (sseg * 4 + q) ^ (srow & 7);
            *(f16x8*)(&As[buf][srow * 64 + c * 8]) = pack8(Ra[2*q], Ra[2*q+1]);
            *(f16x8*)(&Bs[buf][srow * 64 + c * 8]) = pack8(Rb[2*q], Rb[2*q+1]);
        }
    };

    f32x4 acc[4][4] = {};

    auto COMPUTE = [&](int buf) {
        #pragma unroll
        for (int kt = 0; kt < 2; ++kt) {
            f16x8 a[4], b[4];
            #pragma unroll
            for (int im = 0; im < 4; ++im) {
                int row = wm + im * 16 + (l & 15);
                int c   = (kt * 4 + (l >> 4)) ^ (row & 7);
                a[im] = *(const f16x8*)(&As[buf][row * 64 + c * 8]);
            }
            #pragma unroll
            for (int in = 0; in < 4; ++in) {
                int row = wn + in * 16 + (l & 15);
                int c   = (kt * 4 + (l >> 4)) ^ (row & 7);
                b[in] = *(const f16x8*)(&Bs[buf][row * 64 + c * 8]);
            }
            #pragma unroll
            for (int im = 0; im < 4; ++im)
                #pragma unroll
                for (int in = 0; in < 4; ++in)
                    acc[im][in] = __builtin_amdgcn_mfma_f32_16x16x32_f16(
                        a[im], b[in], acc[im][in], 0, 0, 0);
        }
    };

    LD(0);
    ST(0);
    __syncthreads();
    #pragma unroll
    for (int k = 0; k < 3; ++k) {
        LD((k + 1) * 64);        // issue next tile's loads (latency hidden by compute)
        COMPUTE(k & 1);
        ST((k + 1) & 1);         // waits only on its own loads
        __syncthreads();
    }
    COMPUTE(1);

    #pragma unroll
    for (int im = 0; im < 4; ++im)
        #pragma unroll
        for (int in = 0; in < 4; ++in) {
            int n = n0 + wn + in * 16 + (l & 15);
            float bias = (n < 256) ? bf[n] : br[n - 256];
            #pragma unroll
            for (int r = 0; r < 4; ++r) {
                long m = m0 + wm + im * 16 + ((l >> 4) * 4 + r);
                out[m * 512 + n] = acc[im][in][r] + bias;
            }
        }
}

// ---------------------------------------------------------------------------
// Kernel 2: MFMA scan. 8 blocks x 512 threads (8 waves = 2/SIMD for latency
// overlap); block = 16 chains of one direction. Wave w owns output cols
// [32w, 32w+32). Per step/wave: 8 ds_read_b128 (full-K h), 16 MFMA, 8 tanh,
// 8 global stores, 8 prefetch loads, 8 f16 LDS writes. Raw s_barrier +
// lgkmcnt(0) only — global stores/prefetches never drained at the barrier.
// ---------------------------------------------------------------------------
__global__ __launch_bounds__(512, 2) void rnn_scan(
    float* __restrict__ out, const float* __restrict__ hidden,
    const float* __restrict__ Whf, const float* __restrict__ Whr,
    float* __restrict__ hid_out)
{
    __shared__ __align__(16) f16 hbuf[2][16 * 256];

    const int tid = threadIdx.x;
    const int g   = blockIdx.x;        // 0..7
    const int dir = g >> 2;
    const int b0  = (g & 3) * 16;
    const int w   = tid >> 6, l = tid & 63;   // w: 0..7
    const int c15 = l & 15, hi = l >> 4;

    // W_hh B-fragments for this wave's 32 cols: n = 32w+16nt+c15, k = 32kt+8hi+j
    const float* Wh = dir ? Whr : Whf;
    f16x8 Bhh[2][8];
    #pragma unroll
    for (int nt = 0; nt < 2; ++nt) {
        int n = w * 32 + nt * 16 + c15;
        #pragma unroll
        for (int kt = 0; kt < 8; ++kt) {
            const float* p = Wh + (long)n * HID + kt * 32 + hi * 8;
            float4 u0 = ((const float4*)p)[0];
            float4 u1 = ((const float4*)p)[1];
            f16x8 r = { (f16)u0.x, (f16)u0.y, (f16)u0.z, (f16)u0.w,
                        (f16)u1.x, (f16)u1.y, (f16)u1.z, (f16)u1.w };
            Bhh[nt][kt] = r;
        }
    }

    // initial h -> hbuf[0] (f16, swizzled): thread = (chain = tid>>5, chunk = tid&31)
    {
        int chain = tid >> 5;
        int c     = tid & 31;
        const float* hp = hidden + ((long)dir * BATCH + b0 + chain) * HID + c * 8;
        float4 u0 = ((const float4*)hp)[0];
        float4 u1 = ((const float4*)hp)[1];
        f16x8 r = { (f16)u0.x, (f16)u0.y, (f16)u0.z, (f16)u0.w,
                    (f16)u1.x, (f16)u1.y, (f16)u1.z, (f16)u1.w };
        int cs = c ^ (chain & 7);
        *(f16x8*)(&hbuf[0][chain * 256 + cs * 8]) = r;
    }

    // xp/output byte offsets: lane holds (chain = 4hi+r, col = 32w+16nt+c15)
    unsigned off[2][4];
    float    xr[2][4];
    const int t0 = dir ? (T_LEN - 1) : 0;
    #pragma unroll
    for (int nt = 0; nt < 2; ++nt)
        #pragma unroll
        for (int r = 0; r < 4; ++r) {
            int chain = hi * 4 + r;
            int col   = w * 32 + nt * 16 + c15;
            off[nt][r] = (unsigned)((((b0 + chain) * T_LEN + t0) * 512
                                     + dir * 256 + col) * 4);
            xr[nt][r] = *(const float*)((const char*)out + off[nt][r]);
        }

    __syncthreads();

    const int sdelta = dir ? -2048 : 2048;   // +/- one timestep (512 f32)
    float hlast[2][4];

    for (int s = 0; s < T_LEN; ++s) {
        const f16* rb = hbuf[s & 1];
        f16*       wb = hbuf[(s + 1) & 1];
        const int d = (s == T_LEN - 1) ? 0 : sdelta;

        // acc <- xp (bias folded in by the GEMM)
        f32x4 acc[2];
        #pragma unroll
        for (int nt = 0; nt < 2; ++nt)
            #pragma unroll
            for (int r = 0; r < 4; ++r)
                acc[nt][r] = xr[nt][r];

        // prefetch next step's xp (value at d==0 is discarded -> benign)
        #pragma unroll
        for (int nt = 0; nt < 2; ++nt)
            #pragma unroll
            for (int r = 0; r < 4; ++r) {
                off[nt][r] += d;
                xr[nt][r] = *(const float*)((const char*)out + off[nt][r]);
            }

        // h A-fragments: row = chain = c15, k-chunk c = 4kt+hi, swizzled
        f16x8 hfrag[8];
        #pragma unroll
        for (int kt = 0; kt < 8; ++kt) {
            int cs = ((kt * 4 + hi) ^ (c15 & 7));
            hfrag[kt] = *(const f16x8*)(&rb[c15 * 256 + cs * 8]);
        }

        #pragma unroll
        for (int kt = 0; kt < 8; ++kt)
            #pragma unroll
            for (int nt = 0; nt < 2; ++nt)
                acc[nt] = __builtin_amdgcn_mfma_f32_16x16x32_f16(
                    hfrag[kt], Bhh[nt][kt], acc[nt], 0, 0, 0);

        // epilogue: tanh, store f32 out (fire-and-forget), f16 h -> LDS
        #pragma unroll
        for (int nt = 0; nt < 2; ++nt)
            #pragma unroll
            for (int r = 0; r < 4; ++r) {
                float p  = acc[nt][r];
                float e  = __builtin_amdgcn_exp2f(p * 2.885390081777927f);
                float hn = fmaf(-2.0f, __builtin_amdgcn_rcpf(e + 1.0f), 1.0f);
                hlast[nt][r] = hn;
                *(float*)((char*)out + (off[nt][r] - d)) = hn;

                int chain = hi * 4 + r;
                int col   = w * 32 + nt * 16 + c15;
                int cs    = (col >> 3) ^ (chain & 7);
                wb[chain * 256 + cs * 8 + (col & 7)] = (f16)hn;
            }

        asm volatile("s_waitcnt lgkmcnt(0)" ::: "memory");
        __builtin_amdgcn_sched_barrier(0);
        __builtin_amdgcn_s_barrier();
        __builtin_amdgcn_sched_barrier(0);
    }

    #pragma unroll
    for (int nt = 0; nt < 2; ++nt)
        #pragma unroll
        for (int r = 0; r < 4; ++r) {
            int chain = hi * 4 + r;
            int col   = w * 32 + nt * 16 + c15;
            hid_out[((long)dir * BATCH + b0 + chain) * HID + col] = hlast[nt][r];
        }
}

// ---------------------------------------------------------------------------
extern "C" void kernel_launch(void* const* d_in, const int* in_sizes, int n_in,
                              void* d_out, int out_size, void* d_ws, size_t ws_size,
                              hipStream_t stream)
{
    const float* x      = (const float*)d_in[0];  // [B,T,D]
    const float* hidden = (const float*)d_in[1];  // [2,B,H]
    const float* W_ih_f = (const float*)d_in[2];  // [H,D]
    const float* W_hh_f = (const float*)d_in[3];  // [H,H]
    const float* b_f    = (const float*)d_in[4];  // [H]
    const float* W_ih_r = (const float*)d_in[5];
    const float* W_hh_r = (const float*)d_in[6];
    const float* b_r    = (const float*)d_in[7];

    float* outp    = (float*)d_out;                       // [B,T,512]
    float* hid_out = outp + (long)BATCH * T_LEN * 512;    // [2,B,H]

    xproj_gemm<<<dim3(4096), 256, 0, stream>>>(
        x, W_ih_f, W_ih_r, b_f, b_r, outp);

    rnn_scan<<<dim3(8), 512, 0, stream>>>(
        outp, hidden, W_hh_f, W_hh_r, hid_out);
}